// Round 14
// baseline (509.776 us; speedup 1.0000x reference)
//
#include <hip/hip_runtime.h>
#include <cstdint>
#include <math.h>

#define NBATCH 32
#define NSQ 1024
#define NCQ 1024
#define DDIM 256
#define DP 257
#define KQ 128
#define KPAD 288   // 257 padded to /32
#define NFOLD 640  // folded m rows per batch (513 padded to /128)
#define KF2 640    // folded stage-2 K layout pitch (513 used; K=544 passed to GEMM)
#define MXSPLIT 4194304   // float offset between split-K partial buffers

typedef __attribute__((ext_vector_type(8))) short short8;
typedef __attribute__((ext_vector_type(4))) float floatx4;

// ---------------- device helpers ----------------
__device__ __forceinline__ float bf2f(ushort u) { return __uint_as_float(((uint)u) << 16); }
__device__ __forceinline__ ushort f2bf(float f) {
    uint u = __float_as_uint(f);
    return (ushort)((u + 0x7FFFu + ((u >> 16) & 1u)) >> 16);
}
__device__ __forceinline__ void gload16(const void* g, void* l) {
    __builtin_amdgcn_global_load_lds(
        (const __attribute__((address_space(1))) void*)g,
        (__attribute__((address_space(3))) void*)l,
        16, 0, 0);
}
__device__ __forceinline__ float artanh_clip(float x) {
    x = fminf(fmaxf(x, -1.0f + 1e-5f), 1.0f - 1e-5f);
    return 0.5f * (log1pf(x) - log1pf(-x));
}
__device__ __forceinline__ float gelu_f(float x) {
    return 0.5f * x * (1.0f + erff(x * 0.70710678118654752440f));
}
__device__ __forceinline__ float waveRedSum(float v) {
#pragma unroll
    for (int o = 32; o > 0; o >>= 1) v += __shfl_down(v, o, 64);
    return __shfl(v, 0, 64);
}
// three/two interleaved wave reductions (one 6-step dependent chain)
__device__ __forceinline__ void waveRedSum3(float& a, float& b, float& c) {
#pragma unroll
    for (int o = 32; o > 0; o >>= 1) {
        a += __shfl_down(a, o, 64);
        b += __shfl_down(b, o, 64);
        c += __shfl_down(c, o, 64);
    }
    a = __shfl(a, 0, 64); b = __shfl(b, 0, 64); c = __shfl(c, 0, 64);
}
__device__ __forceinline__ void waveRedSum2(float& a, float& b) {
#pragma unroll
    for (int o = 32; o > 0; o >>= 1) {
        a += __shfl_down(a, o, 64);
        b += __shfl_down(b, o, 64);
    }
    a = __shfl(a, 0, 64); b = __shfl(b, 0, 64);
}
__device__ __forceinline__ float blockRedSum(float v, float* buf) {
    int lane = threadIdx.x & 63, wid = threadIdx.x >> 6;
#pragma unroll
    for (int o = 32; o > 0; o >>= 1) v += __shfl_down(v, o, 64);
    __syncthreads();
    if (lane == 0) buf[wid] = v;
    __syncthreads();
    int nw = blockDim.x >> 6;
    float s = buf[0];
    for (int i = 1; i < nw; i++) s += buf[i];
    return s;
}
__device__ __forceinline__ float blockRedMax(float v, float* buf) {
    int lane = threadIdx.x & 63, wid = threadIdx.x >> 6;
#pragma unroll
    for (int o = 32; o > 0; o >>= 1) v = fmaxf(v, __shfl_down(v, o, 64));
    __syncthreads();
    if (lane == 0) buf[wid] = v;
    __syncthreads();
    int nw = blockDim.x >> 6;
    float s = buf[0];
    for (int i = 1; i < nw; i++) s = fmaxf(s, buf[i]);
    return s;
}

// ---------------- bf16 MFMA GEMM (round-8 proven: BK=32, 16KB LDS) ----------------
// C[m,n] = sum_k A[m,k]*B'[k,n] (+bias[n]; biasB used when zb!=0). A,B row-major.
// NSPLIT>1 && !ATOMIC: partial sums to Cv + ks*cOff1 (separate buffers).
// XCD-aware block swizzle: physical flat id f -> logical (f&7)*(nblk/8)+(f>>3)
// so each XCD owns a contiguous tile range (all tiles of a z on one XCD's L2).
template <bool OUT_BF16, bool BIAS, bool ATOMIC, int NSPLIT, bool DUAL>
__global__ __launch_bounds__(256) void mfma_gemm(
    const short* __restrict__ A, int lda, int64_t sA,
    const short* __restrict__ B, int ldb, int64_t sB,
    void* __restrict__ Cv, int ldc, int64_t sC,
    const float* __restrict__ bias, int M, int N, int K,
    const short* __restrict__ A1, const short* __restrict__ B1, int64_t cOff1,
    const float* __restrict__ biasB)
{
    __shared__ short As[128][32];
    __shared__ short Bs[128][32];
    int bx = blockIdx.x, by = blockIdx.y, bz = blockIdx.z;
    {
        const int gx = gridDim.x, gy = gridDim.y;
        const int nblk = gx * gy * gridDim.z;
        if ((nblk & 7) == 0) {
            int flat = bx + gx * (by + gy * bz);
            int logical = (flat & 7) * (nblk >> 3) + (flat >> 3);
            bx = logical % gx; logical /= gx;
            by = logical % gy; bz = logical / gy;
        }
    }
    const int zz = bz;
    int zb, ks, half;
    if (DUAL) { half = zz & 1; zb = zz >> 1; ks = 0; }
    else      { zb = zz / NSPLIT; ks = zz - zb * NSPLIT; half = 0; }
    const short* Ap = (DUAL && half) ? A1 : A;
    const short* Bp = (DUAL && half) ? B1 : B;
    Ap += (int64_t)zb * sA;
    Bp += (int64_t)zb * sB;
    const int kper = K / NSPLIT;
    const int kbeg = ks * kper, kend = kbeg + kper;
    const int m0 = by * 128, n0 = bx * 128;
    const int t = threadIdx.x;
    const int lane = t & 63, w = t >> 6;
    const int wm = (w & 1) * 64, wn = (w >> 1) * 64;
    floatx4 acc[4][4] = {};
    for (int k0 = kbeg; k0 < kend; k0 += 32) {
        {
            int r = t >> 2, c8 = (t & 3) * 8;
            const short* ap = Ap + (int64_t)(m0 + r) * lda + k0 + c8;
            gload16(ap, &As[r][c8]);
            gload16(ap + (int64_t)64 * lda, &As[r + 64][c8]);
            const short* bp = Bp + (int64_t)(n0 + r) * ldb + k0 + c8;
            gload16(bp, &Bs[r][c8]);
            gload16(bp + (int64_t)64 * ldb, &Bs[r + 64][c8]);
        }
        __syncthreads();
        short8 af[4], bfv[4];
#pragma unroll
        for (int i = 0; i < 4; i++)
            af[i] = *(const short8*)&As[wm + 16 * i + (lane & 15)][8 * (lane >> 4)];
#pragma unroll
        for (int i = 0; i < 4; i++)
            bfv[i] = *(const short8*)&Bs[wn + 16 * i + (lane & 15)][8 * (lane >> 4)];
#pragma unroll
        for (int i = 0; i < 4; i++)
#pragma unroll
            for (int j = 0; j < 4; j++)
                acc[i][j] = __builtin_amdgcn_mfma_f32_16x16x32_bf16(af[i], bfv[j], acc[i][j], 0, 0, 0);
        __syncthreads();
    }
    const int q = lane >> 4, c = lane & 15;
    int64_t cbase = (int64_t)zb * sC + ((DUAL && half) ? cOff1 : 0);
    if (NSPLIT > 1 && !ATOMIC) cbase += (int64_t)ks * cOff1;
    const float* bsel = (BIAS && biasB && zb) ? biasB : bias;
#pragma unroll
    for (int j = 0; j < 4; j++) {
        int col = n0 + wn + 16 * j + c;
        float bv = BIAS ? bsel[col] : 0.0f;
#pragma unroll
        for (int i = 0; i < 4; i++) {
            int rowb = m0 + wm + 16 * i + 4 * q;
#pragma unroll
            for (int r = 0; r < 4; r++) {
                float v = acc[i][j][r] + bv;
                int64_t idx = cbase + (int64_t)(rowb + r) * ldc + col;
                if (ATOMIC)       atomicAdd((float*)Cv + idx, v);
                else if (OUT_BF16) ((ushort*)Cv)[idx] = f2bf(v);
                else               ((float*)Cv)[idx] = v;
            }
        }
    }
}

// ---------------- trig table (cos/sin of 2*pi*p/1024, bit-exact args) ----------------
__global__ __launch_bounds__(256) void trigtab_kernel(float* __restrict__ tab) {
    int p = blockIdx.x * 256 + threadIdx.x;   // grid 4 -> p in [0,1024)
    float ang = (6.28318530717958647692f / 1024.0f) * (float)p;
    tab[p] = cosf(ang);
    tab[1024 + p] = sinf(ang);
}

// ---------------- fused constants (table-driven) ----------------
// CS1 rows per block (no int div, k<544 only - GEMM reads K=544); C2/S2 via
// table idx 4p (2*pi/256*p == 2*pi/1024*4p bit-exact); W packs unchanged.
__global__ __launch_bounds__(256) void genconst_kernel(
    const float* __restrict__ tab,
    ushort* CS1c, ushort* CS1s, ushort* C2, ushort* S2,
    const float* __restrict__ WlW, const float* __restrict__ WsW, const float* __restrict__ WcW,
    ushort* Wl, ushort* Ws, ushort* Wc)
{
    __shared__ float lct[1024], lst[1024];
    int blk = blockIdx.x, t = threadIdx.x;
    if (blk < 704) {
        for (int i = t; i < 1024; i += 256) { lct[i] = tab[i]; lst[i] = tab[1024 + i]; }
        __syncthreads();
    }
    if (blk < 640) {
        int n = blk;
        for (int k = t; k < 544; k += 256) {
            float vc, vs;
            if (k <= 512) {
                int p = (n * k) & 1023;
                vc = lct[p];
                vs = (k == 0) ? 0.0f : -lst[p];
            } else { vc = 0.0f; vs = 0.0f; }
            CS1c[n * KF2 + k] = f2bf(vc);
            CS1s[n * KF2 + k] = f2bf(vs);
        }
    } else if (blk < 704) {
        int base = (blk - 640) * 1024;        // 64 blocks x 1024 = 256x256
#pragma unroll
        for (int i = 0; i < 4; i++) {
            int idx = base + t + 256 * i;
            int d = idx >> 8, j = idx & 255;
            int p = ((d * j) & 255) << 2;
            C2[idx] = f2bf(lct[p]);
            S2[idx] = f2bf(lst[p]);
        }
    } else {
        int r = blk - 704;                    // 512 rows
        const float* src; ushort* dst; int srow;
        if (r < 256)      { src = WlW; dst = Wl + r * KPAD;        srow = r + 1; }
        else if (r < 384) { src = WsW; dst = Ws + (r - 256) * KPAD; srow = r - 256 + 1; }
        else              { src = WcW; dst = Wc + (r - 384) * KPAD; srow = r - 384 + 1; }
        dst[t] = (t < DP) ? f2bf(src[(int64_t)srow * DP + t]) : (ushort)0;
        if (t < KPAD - 256) {
            int t2 = t + 256;
            dst[t2] = (t2 < DP) ? f2bf(src[(int64_t)srow * DP + t2]) : (ushort)0;
        }
    }
}

// input prep + m-fold, wave-per-(bp,z)
__global__ __launch_bounds__(256) void prep_fold_kernel(const float* __restrict__ sent,
                                                        const float* __restrict__ comm,
                                                        ushort* __restrict__ XC, ushort* __restrict__ XS) {
    int bp = blockIdx.x;                       // 0..512
    int z = blockIdx.y * 4 + (threadIdx.x >> 6);
    int lane = threadIdx.x & 63;
    int m2 = (1024 - bp) & 1023;
    const float* base = (z < 32) ? sent + (int64_t)z * 262144 : comm + (int64_t)(z - 32) * 262144;
    float4 a = *(const float4*)(base + bp * 256 + 4 * lane);
    float4 b = *(const float4*)(base + m2 * 256 + 4 * lane);
    if (z >= 32) {
        float s1 = a.x * a.x + a.y * a.y + a.z * a.z + a.w * a.w;
        float s2 = b.x * b.x + b.y * b.y + b.z * b.z + b.w * b.w;
        waveRedSum2(s1, s2);
        float yn1 = sqrtf(fmaxf(s1, 1e-15f));
        float f1 = artanh_clip(yn1) / yn1;
        a.x *= f1; a.y *= f1; a.z *= f1; a.w *= f1;
        float yn2 = sqrtf(fmaxf(s2, 1e-15f));
        float f2v = artanh_clip(yn2) / yn2;
        b.x *= f2v; b.y *= f2v; b.z *= f2v; b.w *= f2v;
    }
    int64_t o = ((int64_t)z * NFOLD + bp) * 256 + 4 * lane;
    bool single = (bp == 0) || (bp == 512);
    ushort4 oc;
    oc.x = f2bf(single ? a.x : a.x + b.x);
    oc.y = f2bf(single ? a.y : a.y + b.y);
    oc.z = f2bf(single ? a.z : a.z + b.z);
    oc.w = f2bf(single ? a.w : a.w + b.w);
    *(ushort4*)(XC + o) = oc;
    if (!single) {
        ushort4 os;
        os.x = f2bf(a.x - b.x); os.y = f2bf(a.y - b.y);
        os.z = f2bf(a.z - b.z); os.w = f2bf(a.w - b.w);
        *(ushort4*)(XS + o) = os;
    }
}

// euclid_to_lorentz, wave-per-row, n-fold combine, exp-based sinh/cosh
// (memory-bound at ~105 MB; wave-per-row form is the measured-best variant)
__global__ __launch_bounds__(256) void e2l_kernel(const ushort* __restrict__ YcYs,
                                                  ushort* __restrict__ Lsb, ushort* __restrict__ Lcb) {
    int64_t row = (int64_t)blockIdx.x * 4 + (threadIdx.x >> 6);   // 0..65535
    int lane = threadIdx.x & 63;
    int z = (int)(row >> 10), n = (int)(row & 1023);
    int np = (n <= 512) ? n : 1024 - n;
    float sgn = (n <= 512) ? 1.0f : -1.0f;
    const ushort* base = YcYs + (int64_t)z * 327680 + np * 256 + 4 * lane;
    ushort4 uc = *(const ushort4*)base;
    ushort4 us = *(const ushort4*)(base + 163840);
    float v0 = bf2f(uc.x) + sgn * bf2f(us.x);
    float v1 = bf2f(uc.y) + sgn * bf2f(us.y);
    float v2 = bf2f(uc.z) + sgn * bf2f(us.z);
    float v3 = bf2f(uc.w) + sgn * bf2f(us.w);
    float s = waveRedSum(v0 * v0 + v1 * v1 + v2 * v2 + v3 * v3);
    float xn = sqrtf(fmaxf(s, 1e-15f)) + 1e-5f;
    float sc = fminf(1.0f, 2.0f / xn);
    float s2 = fmaxf(s * sc * sc, 1e-15f);
    float vn = sqrtf(s2);
    float e = expf(vn);
    float ei = 1.0f / e;
    float shv = (vn < 1e-4f) ? 1.0f : (e - ei) * 0.5f / vn;
    float fac = shv * sc;
    ushort* ob = (row < 32768 ? Lsb + row * KPAD : Lcb + (row - 32768) * KPAD);
    ob[1 + 4 * lane + 0] = f2bf(fac * v0);
    ob[1 + 4 * lane + 1] = f2bf(fac * v1);
    ob[1 + 4 * lane + 2] = f2bf(fac * v2);
    ob[1 + 4 * lane + 3] = f2bf(fac * v3);
    if (lane == 0) ob[0] = f2bf((e + ei) * 0.5f);
    if (lane < KPAD - DP) ob[DP + lane] = 0;
}

// lorentz_linear time fill (in place on bf16 rows of 288)
__global__ __launch_bounds__(256) void lnorm_kernel(ushort* __restrict__ Llin_bf) {
    int64_t row = (int64_t)blockIdx.x * 4 + (threadIdx.x >> 6);
    int lane = threadIdx.x & 63;
    ushort* ob = Llin_bf + row * KPAD;
    float s = 0.f;
#pragma unroll
    for (int i = 0; i < 4; i++) { float v = bf2f(ob[1 + 4 * lane + i]); s += v * v; }
    s = waveRedSum(s);
    if (lane == 0) ob[0] = f2bf(sqrtf(s + 1.0f));
    if (lane < KPAD - DP) ob[DP + lane] = 0;
}

// fused to_poincare + transpose on H rows of 128 (HsA+HcA via z in [0,64)).
// Block = 32 rows x 128 cols of one z-batch. Sector-coalesced global access
// (4 consecutive lanes x 16B contiguous per instruction). Row norms via
// 3-step 8-lane shfl_xor. Writes normalized rows back in place AND transposed.
__global__ __launch_bounds__(256) void poincT_kernel(ushort* __restrict__ H, ushort* __restrict__ HT) {
    __shared__ ushort tile[32][132];   // pitch 132: 8B-aligned rows; phase-2 reads ~4-way (cheap)
    int z = blockIdx.y;                // 0..63
    int n0 = blockIdx.x * 32;
    ushort* ib = H + (int64_t)z * 131072;
    ushort* ob = HT + (int64_t)z * 131072;
    int t = threadIdx.x;
    {
        int row = t >> 3;              // 0..31
        int s0 = (t & 7) * 8;          // lanes 0-3 -> bytes 0..63 (full sector/instr)
        ushort* src = ib + (int64_t)(n0 + row) * 128;
        uint4 va = *(const uint4*)(src + s0);
        uint4 vb = *(const uint4*)(src + s0 + 64);
        float fa[8], fb[8];
        const ushort* pa = (const ushort*)&va;
        const ushort* pb = (const ushort*)&vb;
        float s = 0.f;
#pragma unroll
        for (int i = 0; i < 8; i++) {
            fa[i] = bf2f(pa[i]); fb[i] = bf2f(pb[i]);
            s += fa[i] * fa[i] + fb[i] * fb[i];
        }
        s += __shfl_xor(s, 1, 64);
        s += __shfl_xor(s, 2, 64);
        s += __shfl_xor(s, 4, 64);
        float inv = 1.0f / (sqrtf(s + 1.0f) + 1.0f);
        ushort ga[8], gb[8];
#pragma unroll
        for (int i = 0; i < 8; i++) { ga[i] = f2bf(fa[i] * inv); gb[i] = f2bf(fb[i] * inv); }
        *(uint4*)(src + s0) = *(const uint4*)ga;
        *(uint4*)(src + s0 + 64) = *(const uint4*)gb;
        *(ushort4*)&tile[row][s0] = *(const ushort4*)&ga[0];
        *(ushort4*)&tile[row][s0 + 4] = *(const ushort4*)&ga[4];
        *(ushort4*)&tile[row][s0 + 64] = *(const ushort4*)&gb[0];
        *(ushort4*)&tile[row][s0 + 68] = *(const ushort4*)&gb[4];
    }
    __syncthreads();
    {
#pragma unroll
        for (int p = 0; p < 2; p++) {
            int j = p * 64 + (t >> 2);     // out row 0..127
            int nq = (t & 3) * 8;          // 4 lanes cover 32 ushorts = one 64B sector
            ushort g[8];
#pragma unroll
            for (int k = 0; k < 8; k++) g[k] = tile[nq + k][j];
            *(uint4*)(ob + (int64_t)j * 1024 + n0 + nq) = *(const uint4*)g;
        }
    }
}

// per-batch 1024x1024 bf16 gelu + transpose, 64x64 tiles.
// Sector-coalesced: every global load/store instruction covers full 64B sectors
// (4 consecutive lanes x 16B contiguous per row). Partials folded over the 4
// consecutive lanes via shfl_xor. 16 chunks per batch.
__global__ __launch_bounds__(256) void tmat_kernel(ushort* __restrict__ inout, ushort* __restrict__ outp,
                                                   float* __restrict__ rowpart, float* __restrict__ colpart) {
    __shared__ ushort tile[64][68];   // pitch 68 ushorts: 8B-aligned vector writes
    int z = blockIdx.z;
    int r0 = blockIdx.x * 64, c0 = blockIdx.y * 64;
    ushort* ib = inout + (int64_t)z * 1048576;
    ushort* ob = outp + (int64_t)z * 1048576;
    int t = threadIdx.x;
    int row = t >> 2;            // 0..63
    int cq = (t & 3) * 8;        // 8-ushort (16B) segment; lanes 0-3 -> 64B contiguous
    {
        ushort* src = ib + (int64_t)(r0 + row) * 1024 + c0;
        float rsum = 0.f;
#pragma unroll
        for (int s = 0; s < 2; s++) {
            int cb = cq + 32 * s;
            uint4 v = *(const uint4*)(src + cb);
            ushort g[8];
            const ushort* pv = (const ushort*)&v;
#pragma unroll
            for (int k = 0; k < 8; k++) {
                g[k] = f2bf(gelu_f(bf2f(pv[k])));
                float fb = bf2f(g[k]);
                if (!(c0 == 0 && cb == 0 && k == 0)) rsum += fb * fb;  // exclude global col 0
            }
            *(uint4*)(src + cb) = *(const uint4*)g;            // gelu'd row-major write-back
            *(ushort4*)&tile[row][cb] = *(const ushort4*)&g[0];
            *(ushort4*)&tile[row][cb + 4] = *(const ushort4*)&g[4];
        }
        rsum += __shfl_xor(rsum, 1, 64);
        rsum += __shfl_xor(rsum, 2, 64);
        if ((t & 3) == 0)
            rowpart[((int64_t)(z * 16 + blockIdx.y)) * 1024 + r0 + row] = rsum;
    }
    __syncthreads();
    {
        int i2 = row;            // out-row within tile (orig col c0+i2)
        ushort* dst = ob + (int64_t)(c0 + i2) * 1024 + r0;
        float csum = 0.f;
#pragma unroll
        for (int s = 0; s < 2; s++) {
            int cb = cq + 32 * s;
            ushort g[8];
#pragma unroll
            for (int k = 0; k < 8; k++) {
                g[k] = tile[cb + k][i2];
                float a = bf2f(g[k]);
                csum += a * a;
            }
            *(uint4*)(dst + cb) = *(const uint4*)g;            // full 64B sector per 4 lanes
        }
        csum += __shfl_xor(csum, 1, 64);
        csum += __shfl_xor(csum, 2, 64);
        if ((t & 3) == 0)
            colpart[((int64_t)(z * 16 + blockIdx.x)) * 1024 + c0 + i2] = csum;
    }
}

// fold partials: write time col into Lmat + LmatT row0, xnrow, final colsum
// (col 0 of colsum = sum of time^2, computed here exactly). 16 chunks per batch.
__global__ __launch_bounds__(256) void combine_kernel(
    const float* __restrict__ rowpart, const float* __restrict__ colpart,
    ushort* __restrict__ Lmat, ushort* __restrict__ LmatT,
    float* __restrict__ xnrow, float* __restrict__ colsum)
{
    __shared__ float red[4];
    int b = blockIdx.x, t = threadIdx.x;
    float t2 = 0.f;
#pragma unroll
    for (int i = 0; i < 4; i++) {
        int n = t + 256 * i;
        const float* rp = rowpart + (int64_t)b * 16384 + n;
        float s = 0.f;
#pragma unroll
        for (int c = 0; c < 16; c++) s += rp[c * 1024];
        float tim = sqrtf(1.0f + s);
        ushort tb = f2bf(tim);
        Lmat[((int64_t)(b * 1024 + n)) * 1024] = tb;
        LmatT[(int64_t)b * 1048576 + n] = tb;
        xnrow[b * 1024 + n] = sqrtf(fmaxf(1.0f + 2.0f * s, 1e-15f));
        t2 += tim * tim;
    }
#pragma unroll
    for (int i = 0; i < 4; i++) {
        int m = t + 256 * i;
        const float* cp = colpart + (int64_t)b * 16384 + m;
        float s = 0.f;
#pragma unroll
        for (int c = 0; c < 16; c++) s += cp[c * 1024];
        if (m > 0) colsum[b * 1024 + m] = s;
    }
    float tt = blockRedSum(t2, red);
    if (t == 0) colsum[b * 1024] = tt;
}

// column factor for mobius scale: fac_c[b,m] (reads precomputed colsum)
__global__ __launch_bounds__(256) void colfac_kernel(const float* __restrict__ colsum,
                                                     const float* __restrict__ mxcT,
                                                     float* __restrict__ fac_c) {
    int b = blockIdx.x; int m = blockIdx.y * 256 + threadIdx.x;
    float xn = sqrtf(fmaxf(colsum[b * NCQ + m], 1e-15f));
    const float* base = mxcT + (int64_t)b * KQ * NCQ + m;
    const float* base2 = base + MXSPLIT;
    float sm = 0.f;
    for (int j = 0; j < KQ; j++) {
        float v = base[j * NCQ] + base2[j * NCQ];
        sm += v * v;
    }
    float mxn = sqrtf(fmaxf(sm, 1e-15f));
    fac_c[b * NCQ + m] = tanhf(mxn / xn * artanh_clip(xn)) / mxn;
}

// Hs path rowwise chain -> logits.
// 8 rows per wave (8 lanes/row, 16 elems/lane): per-row transcendental chain
// amortized 8x; reductions are 3-step 8-lane shfl_xor trees.
__global__ __launch_bounds__(256) void rowops_s_kernel(
    const ushort* __restrict__ Hsa, const float* __restrict__ mxs,
    const float* __restrict__ xnrow, const float* __restrict__ whs,
    float* __restrict__ logits)
{
    const int t = threadIdx.x;
    const int lane = t & 63;
    const int wid = t >> 6;
    const int sub = lane & 7;         // lane within row-group
    const int rg  = lane >> 3;        // row within wave (0..7)
    const int64_t row = (int64_t)blockIdx.x * 32 + wid * 8 + rg;
    const ushort* p = Hsa + row * KQ + sub * 16;
    const float*  q = mxs + row * KQ + sub * 16;

    float pf[16], qf[16];
    {
        uint4 u0 = *(const uint4*)p;
        uint4 u1 = *(const uint4*)(p + 8);
        const ushort* pu0 = (const ushort*)&u0;
        const ushort* pu1 = (const ushort*)&u1;
#pragma unroll
        for (int i = 0; i < 8; i++) { pf[i] = bf2f(pu0[i]); pf[8 + i] = bf2f(pu1[i]); }
    }
#pragma unroll
    for (int i = 0; i < 16; i += 4) {
        float4 a  = *(const float4*)(q + i);
        float4 b2 = *(const float4*)(q + i + MXSPLIT);
        qf[i + 0] = a.x + b2.x; qf[i + 1] = a.y + b2.y;
        qf[i + 2] = a.z + b2.z; qf[i + 3] = a.w + b2.w;
    }
    // Round A: R1=sum q^2, R2=sum p*q, R3=sum p^2
    float r1 = 0.f, r2 = 0.f, r3 = 0.f;
#pragma unroll
    for (int i = 0; i < 16; i++) {
        r1 += qf[i] * qf[i]; r2 += pf[i] * qf[i]; r3 += pf[i] * pf[i];
    }
#pragma unroll
    for (int o = 4; o > 0; o >>= 1) {
        r1 += __shfl_xor(r1, o, 64);
        r2 += __shfl_xor(r2, o, 64);
        r3 += __shfl_xor(r3, o, 64);
    }
    float mxn = sqrtf(fmaxf(r1, 1e-15f));
    float xn = xnrow[row];
    float fac = tanhf(mxn / xn * artanh_clip(xn)) / mxn;
    float xy = fac * r2;
    float x2 = r3;
    float y2 = fac * fac * r1;
    float ca = 1.f + 2.f * xy + y2, cb = 1.f - x2;
    float den = fmaxf(1.f + 2.f * xy + x2 * y2, 1e-15f);
    float hn2 = (ca * ca * x2 + 2.f * ca * cb * xy + cb * cb * y2) / (den * den);
    float hn = sqrtf(fmaxf(hn2, 1e-15f));
    float uf = artanh_clip(hn) / hn;
    float ufd = uf / den;
    float cbf = cb * fac;
    float wv[16];
#pragma unroll
    for (int i = 0; i < 16; i += 4) *(float4*)&wv[i] = *(const float4*)(whs + sub * 16 + i);
    // Round B: R4=sum g^2, R5=sum g*whs
    float r4 = 0.f, r5 = 0.f;
#pragma unroll
    for (int i = 0; i < 16; i++) {
        float g = gelu_f(ufd * (ca * pf[i] + cbf * qf[i]));
        r4 += g * g;
        r5 += g * wv[i];
    }
#pragma unroll
    for (int o = 4; o > 0; o >>= 1) {
        r4 += __shfl_xor(r4, o, 64);
        r5 += __shfl_xor(r5, o, 64);
    }
    float gn = sqrtf(fmaxf(r4, 1e-15f));
    float ef = tanhf(gn) / gn;
    float dot = ef * r5;
    float Hn = sqrtf(fmaxf(ef * ef * r4, 1e-15f));
    float mxn2 = sqrtf(fmaxf(dot * dot, 1e-15f));
    float lg = tanhf(mxn2 / Hn * artanh_clip(Hn)) * dot / mxn2;
    if (sub == 0) logits[row] = lg;
}

// Hc path rowwise chain: wave-per-row (16 elems/lane), applies fac on the fly,
// reads two mx splits, writes combined Hc into split A. 2 reduction rounds.
__global__ __launch_bounds__(256) void rowops_c_kernel(const ushort* __restrict__ HcAT,
                                                       float* __restrict__ mx,
                                                       const float* __restrict__ fac_c) {
    int64_t row = (int64_t)blockIdx.x * 4 + (threadIdx.x >> 6);   // 0..4095
    int lane = threadIdx.x & 63;
    int b = (int)(row >> 7);
    const ushort* xb = HcAT + row * (int64_t)NCQ + 16 * lane;
    float* yb = mx + row * (int64_t)NCQ + 16 * lane;
    const float* fb = fac_c + b * NCQ + 16 * lane;
    float xv[16], yv[16];
    {
        uint4 u0 = *(const uint4*)xb;
        uint4 u1 = *(const uint4*)(xb + 8);
        const ushort* pu0 = (const ushort*)&u0;
        const ushort* pu1 = (const ushort*)&u1;
#pragma unroll
        for (int i = 0; i < 8; i++) { xv[i] = bf2f(pu0[i]); xv[8 + i] = bf2f(pu1[i]); }
    }
#pragma unroll
    for (int i = 0; i < 16; i += 4) {
        float4 v1 = *(const float4*)(yb + i);
        float4 v2 = *(const float4*)(yb + i + MXSPLIT);
        float4 fv = *(const float4*)(fb + i);
        yv[i + 0] = fv.x * (v1.x + v2.x);
        yv[i + 1] = fv.y * (v1.y + v2.y);
        yv[i + 2] = fv.z * (v1.z + v2.z);
        yv[i + 3] = fv.w * (v1.w + v2.w);
    }
    // Round A: xy, x2, y2 (interleaved)
    float xy = 0.f, x2 = 0.f, y2 = 0.f;
#pragma unroll
    for (int i = 0; i < 16; i++) { xy += xv[i] * yv[i]; x2 += xv[i] * xv[i]; y2 += yv[i] * yv[i]; }
    waveRedSum3(xy, x2, y2);
    float ca = 1.f + 2.f * xy + y2, cb = 1.f - x2;
    float den = fmaxf(1.f + 2.f * xy + x2 * y2, 1e-15f);
    float hn2 = (ca * ca * x2 + 2.f * ca * cb * xy + cb * cb * y2) / (den * den);
    float hn = sqrtf(fmaxf(hn2, 1e-15f));
    float uf = artanh_clip(hn) / hn;
    float g[16]; float gn2 = 0.f;
#pragma unroll
    for (int i = 0; i < 16; i++) {
        float h = (ca * xv[i] + cb * yv[i]) / den;
        g[i] = gelu_f(uf * h);
        gn2 += g[i] * g[i];
    }
    gn2 = waveRedSum(gn2);
    float gn = sqrtf(fmaxf(gn2, 1e-15f));
    float ef = tanhf(gn) / gn;
#pragma unroll
    for (int i = 0; i < 16; i += 4) {
        float4 o = {ef * g[i], ef * g[i + 1], ef * g[i + 2], ef * g[i + 3]};
        *(float4*)(yb + i) = o;
    }
}

// Ac logits
__global__ __launch_bounds__(256) void logitsc_kernel(const float* __restrict__ Hc, const float* __restrict__ whc, float* __restrict__ lgc) {
    int b = blockIdx.x; int m = blockIdx.y * 256 + threadIdx.x;
    const float* base = Hc + (int64_t)b * KQ * NCQ + m;
    float s1 = 0.f, s2 = 0.f;
    for (int j = 0; j < KQ; j++) { float v = base[j * NCQ]; s1 += v * whc[j]; s2 += v * v; }
    float xn = sqrtf(fmaxf(s2, 1e-15f));
    float mxn = sqrtf(fmaxf(s1 * s1, 1e-15f));
    lgc[b * NCQ + m] = tanhf(mxn / xn * artanh_clip(xn)) * s1 / mxn;
}

// fused softmax for lgs|lgc -> AsOut|AcOut, grid 64
__global__ __launch_bounds__(256) void softmax_kernel(const float* __restrict__ lg, float* __restrict__ outp) {
    __shared__ float red[4];
    int b = blockIdx.x; int t = threadIdx.x;
    const float* x = lg + b * 1024;
    float v[4]; float m = -1e30f;
#pragma unroll
    for (int i = 0; i < 4; i++) { v[i] = x[t + 256 * i]; m = fmaxf(m, v[i]); }
    m = blockRedMax(m, red);
    float s = 0.f;
#pragma unroll
    for (int i = 0; i < 4; i++) { v[i] = expf(v[i] - m); s += v[i]; }
    s = blockRedSum(s, red);
    float inv = 1.0f / s;
#pragma unroll
    for (int i = 0; i < 4; i++) outp[b * 1024 + t + 256 * i] = v[i] * inv;
}

// centroid stage A on bf16 L (stride 288, time at col 0)
__global__ __launch_bounds__(320) void centroidA_kernel(
    const ushort* __restrict__ Lsb, const ushort* __restrict__ Lcb,
    const float* __restrict__ As, const float* __restrict__ Ac,
    float* __restrict__ part)
{
    int b = blockIdx.x;
    int which = blockIdx.y;
    int chunk = blockIdx.z;
    const ushort* L = which ? Lcb : Lsb;
    const float* w = which ? Ac : As;
    int t = threadIdx.x;
    if (t >= DP) return;
    const ushort* Lb = L + (int64_t)b * NSQ * KPAD + (int64_t)chunk * 128 * KPAD + t;
    const float* wb = w + b * NSQ + chunk * 128;
    float s = 0.f;
    for (int n = 0; n < 128; n++) s += wb[n] * bf2f(Lb[(int64_t)n * KPAD]);
    part[((int64_t)((b * 2 + which) * 8 + chunk)) * 264 + t] = s;
}
__global__ __launch_bounds__(320) void centroidB_kernel(
    const float* __restrict__ part, float* __restrict__ co_s, float* __restrict__ co_c)
{
    int b = blockIdx.x;
    int which = blockIdx.y;
    int t = threadIdx.x;
    if (t >= DP) return;
    const float* p = part + (int64_t)(b * 2 + which) * 8 * 264 + t;
    float s = 0.f;
#pragma unroll
    for (int c = 0; c < 8; c++) s += p[c * 264];
    (which ? co_c : co_s)[b * DP + t] = s;
}

__global__ __launch_bounds__(256) void final_kernel(const float* __restrict__ co_s, const float* __restrict__ co_c, float* __restrict__ outp) {
    __shared__ float red[4];
    int b = blockIdx.x, t = threadIdx.x;
    float zmine[2];
    for (int w = 0; w < 2; w++) {
        const float* co = (w ? co_c : co_s) + b * DP;
        float at = co[0];
        float asp = co[1 + t];
        float ssp = blockRedSum(asp * asp, red);
        float li = ssp - at * at;
        float den = sqrtf(fmaxf(fabsf(li), 1e-8f));
        float xt = at / den, xsp = asp / den;
        float s2 = blockRedSum(xsp * xsp, red);
        float nrm = sqrtf(fmaxf(s2, 1e-15f));
        float ac = acoshf(fmaxf(xt, 1.0f + 1e-7f));
        zmine[w] = ac * xsp / nrm;
    }
    float vn2 = blockRedSum(zmine[0] * zmine[0] + zmine[1] * zmine[1], red);
    float vn = sqrtf(fmaxf(vn2, 1e-15f));
    float sc = sinhf(vn) / vn;
    if (t == 0) outp[b * 513] = coshf(vn);
    outp[b * 513 + 1 + t] = sc * zmine[0];
    outp[b * 513 + 1 + 256 + t] = sc * zmine[1];
}

// ---------------- host launcher ----------------
extern "C" void kernel_launch(void* const* d_in, const int* in_sizes, int n_in,
                              void* d_out, int out_size, void* d_ws, size_t ws_size,
                              hipStream_t stream)
{
    const float* sent = (const float*)d_in[0];
    const float* comm = (const float*)d_in[1];
    const float* WlW  = (const float*)d_in[2];
    const float* Wlb  = (const float*)d_in[3];
    const float* WcW  = (const float*)d_in[4];
    const float* Wcb  = (const float*)d_in[5];
    const float* WsW  = (const float*)d_in[6];
    const float* Wsb  = (const float*)d_in[7];
    const float* whs  = (const float*)d_in[8];
    const float* whc  = (const float*)d_in[9];
    float* out = (float*)d_out;
    (void)in_sizes; (void)n_in; (void)out_size; (void)ws_size;

    float* ws = (float*)d_ws;
    size_t off = 0;
    auto take = [&](size_t n) { float* p = ws + off; off += n; return p; };
    float*  xnrow = take(32768);
    float*  fac_c = take(32768);
    float*  lgs   = take(32768);   // contiguous with lgc
    float*  lgc   = take(32768);
    float*  co_s  = take(8224);
    float*  co_c  = take(8224);
    float*  trigtab = take(2048);
    ushort* Ls_bf = (ushort*)take(4718592);   // contiguous with Lc_bf
    ushort* Lc_bf = (ushort*)take(4718592);
    ushort* Wl_bf = (ushort*)take(36864);
    ushort* Ws_bf = (ushort*)take(18432);
    ushort* Wc_bf = (ushort*)take(18432);
    ushort* HsA_bf = (ushort*)take(2097152);  // contiguous with HcA_bf
    ushort* HcA_bf = (ushort*)take(2097152);
    float*  part_cn   = take(1048576);        // rowpart (32 x 16 x 1024 used)
    float*  part_cent = take(135168);
    ushort* LmatT_bf  = (ushort*)take(16777216);  // 32x1024x1024 bf16
    float*  F     = take(33554432);               // total ~249 MiB

    // Phase overlays in F (float offsets)
    ushort* XC_bf   = (ushort*)F;                 // [P1] 5.24M fl
    ushort* XS_bf   = (ushort*)(F + 5242880);     // [P1] 5.24M fl
    ushort* Ff_bf   = (ushort*)(F + 10485760);    // [P1] 10.49M fl
    ushort* CS1c    = (ushort*)(F + 20971520);    // [P1] 204800 fl
    ushort* CS1s    = (ushort*)(F + 21176320);    // [P1] 204800 fl
    ushort* C2_bf   = (ushort*)(F + 21381120);    // [P1] 32k fl
    ushort* S2_bf   = (ushort*)(F + 21413888);    // [P1] 32k fl
    ushort* YcYs    = (ushort*)F;                 // [P1] aliases XC/XS; 10.49M fl
    ushort* Lmat_bf = (ushort*)F;                 // [P3-P5] 16.78M fl
    ushort* Llin_bf = (ushort*)(F + 29360128);    // [P2-P3] 4.72M fl (dead after Lmat GEMM)
    float*  mx      = F + 16777216;               // [P5] 2 x 4.19M fl split buffers
    ushort* HsAT    = (ushort*)(F + 25165824);    // [P5] 2.1M fl (contiguous with HcAT)
    ushort* HcAT    = (ushort*)(F + 27262976);    // [P5] 2.1M fl
    float*  colpart = F + 29360128;               // [P4-P5] 524288 fl (reuses dead Llin)
    float*  colsum  = F + 30408704;               // [P4-P5] 32k fl

    float* AsOut = out + 16416;
    float* AcOut = out + 16416 + 32768;

    dim3 blk(256);
    const short* NUL = nullptr;

    trigtab_kernel<<<4, 256, 0, stream>>>(trigtab);
    genconst_kernel<<<1216, 256, 0, stream>>>(trigtab, CS1c, CS1s, C2_bf, S2_bf,
                                              WlW, WsW, WcW, Wl_bf, Ws_bf, Wc_bf);

    // ---- input prep + m-fold ----
    prep_fold_kernel<<<dim3(513, 16), blk, 0, stream>>>(sent, comm, XC_bf, XS_bf);
    // stage-1 DUAL: Ff[:, :640] = C2 . XC^T ; Ff[:, 640:] = S2 . XS^T
    mfma_gemm<true,false,false,1,true><<<dim3(5,2,128), blk, 0, stream>>>(
        (const short*)C2_bf,256,0, (const short*)XC_bf,256,(int64_t)NFOLD*256, Ff_bf,1280,(int64_t)256*1280,
        nullptr, 256,NFOLD,256, (const short*)S2_bf, (const short*)XS_bf, 640, nullptr);
    // stage-2 DUAL (n-folded): Yc = CS1c . Fc^T ; Ys = CS1s . Fs^T
    // K trimmed 640->544: CS1c/CS1s cols >=513 are exactly zero -> bit-exact result.
    mfma_gemm<true,false,false,1,true><<<dim3(2,5,128), blk, 0, stream>>>(
        (const short*)CS1c,KF2,0, (const short*)Ff_bf,1280,(int64_t)256*1280, YcYs,256,327680,
        nullptr, NFOLD,256,544, (const short*)CS1s, (const short*)(Ff_bf+640), 163840, nullptr);
    e2l_kernel<<<16384, blk, 0, stream>>>(YcYs, Ls_bf, Lc_bf);

    // ---- L = lorentz_linear(Lc, Wl): space cols bf16 straight into Llin_bf[.,1:] ----
    mfma_gemm<true,true,false,1,false><<<dim3(2,256,1), blk, 0, stream>>>(
        (const short*)Lc_bf,KPAD,0, (const short*)Wl_bf,KPAD,0, (void*)(Llin_bf+1),KPAD,0,
        Wlb+1, 32768,256,KPAD, NUL, NUL, 0, nullptr);
    lnorm_kernel<<<8192, blk, 0, stream>>>(Llin_bf);

    // ---- Lmat = einsum(Ls, Llin) RAW in bf16 (plain scalar epilogue; gelu in tmat) ----
    mfma_gemm<true,false,false,1,false><<<dim3(8,8,32), blk, 0, stream>>>(
        (const short*)Ls_bf,KPAD,294912, (const short*)Llin_bf,KPAD,294912, Lmat_bf,1024,1048576,
        nullptr, 1024,1024,KPAD, NUL, NUL, 0, nullptr);
    // gelu + transpose + write-back + fused row/col sumsq partials, then fold
    tmat_kernel<<<dim3(16,16,32), blk, 0, stream>>>(Lmat_bf, LmatT_bf, part_cn, colpart);
    combine_kernel<<<32, blk, 0, stream>>>(part_cn, colpart, Lmat_bf, LmatT_bf, xnrow, colsum);

    // ---- Hs_a / Hc_a: bf16 + per-z bias straight into HsA_bf|HcA_bf ----
    mfma_gemm<true,true,false,1,false><<<dim3(1,256,2), blk, 0, stream>>>(
        (const short*)Ls_bf,KPAD,9437184, (const short*)Ws_bf,KPAD,36864, HsA_bf,128,4194304,
        Wsb+1, 32768,128,KPAD, NUL, NUL, 0, Wcb+1);
    // fused poincare-normalize + transpose (HsA->HsAT, HcA->HcAT in one launch)
    poincT_kernel<<<dim3(32,64), blk, 0, stream>>>(HsA_bf, HsAT);

    // ---- Hs path: mx_s = Lmat . Hc_a (split-K=2, dual partial buffers) ----
    mfma_gemm<false,false,false,2,false><<<dim3(1,8,64), blk, 0, stream>>>(
        (const short*)Lmat_bf,1024,1048576, (const short*)HcAT,1024,131072, mx,128,131072,
        nullptr, 1024,128,1024, NUL, NUL, MXSPLIT, nullptr);
    rowops_s_kernel<<<1024, blk, 0, stream>>>(HsA_bf, mx, xnrow, whs, lgs);

    // ---- Hc path: mx_cT = Hs_a^T . Lmat (all-fast via HsAT + LmatT; split-K=2) ----
    mfma_gemm<false,false,false,2,false><<<dim3(8,1,64), blk, 0, stream>>>(
        (const short*)HsAT,1024,131072, (const short*)LmatT_bf,1024,1048576, mx,1024,131072,
        nullptr, 128,1024,1024, NUL, NUL, MXSPLIT, nullptr);
    colfac_kernel<<<dim3(32,4), blk, 0, stream>>>(colsum, mx, fac_c);
    rowops_c_kernel<<<1024, blk, 0, stream>>>(HcAT, mx, fac_c);
    logitsc_kernel<<<dim3(32,4), blk, 0, stream>>>(mx, whc, lgc);

    // ---- softmaxes / centroids / concat ----
    softmax_kernel<<<64, blk, 0, stream>>>(lgs, AsOut);
    centroidA_kernel<<<dim3(32,2,8), 320, 0, stream>>>(Ls_bf, Lc_bf, AsOut, AcOut, part_cent);
    centroidB_kernel<<<dim3(32,2), 320, 0, stream>>>(part_cent, co_s, co_c);
    final_kernel<<<32, blk, 0, stream>>>(co_s, co_c, out);
}

// Round 15
// 456.690 us; speedup vs baseline: 1.1162x; 1.1162x over previous
//
#include <hip/hip_runtime.h>
#include <cstdint>
#include <math.h>

#define NBATCH 32
#define NSQ 1024
#define NCQ 1024
#define DDIM 256
#define DP 257
#define KQ 128
#define KPAD 288   // 257 padded to /32
#define NFOLD 640  // folded m rows per batch (513 padded to /128)
#define KF2 640    // folded stage-2 K layout pitch (513 used; K=544 passed to GEMM)
#define MXSPLIT 4194304   // float offset between split-K partial buffers

typedef __attribute__((ext_vector_type(8))) short short8;
typedef __attribute__((ext_vector_type(4))) float floatx4;

// ---------------- device helpers ----------------
__device__ __forceinline__ float bf2f(ushort u) { return __uint_as_float(((uint)u) << 16); }
__device__ __forceinline__ ushort f2bf(float f) {
    uint u = __float_as_uint(f);
    return (ushort)((u + 0x7FFFu + ((u >> 16) & 1u)) >> 16);
}
__device__ __forceinline__ void gload16(const void* g, void* l) {
    __builtin_amdgcn_global_load_lds(
        (const __attribute__((address_space(1))) void*)g,
        (__attribute__((address_space(3))) void*)l,
        16, 0, 0);
}
__device__ __forceinline__ float artanh_clip(float x) {
    x = fminf(fmaxf(x, -1.0f + 1e-5f), 1.0f - 1e-5f);
    return 0.5f * (log1pf(x) - log1pf(-x));
}
__device__ __forceinline__ float gelu_f(float x) {
    return 0.5f * x * (1.0f + erff(x * 0.70710678118654752440f));
}
__device__ __forceinline__ float waveRedSum(float v) {
#pragma unroll
    for (int o = 32; o > 0; o >>= 1) v += __shfl_down(v, o, 64);
    return __shfl(v, 0, 64);
}
// three/two interleaved wave reductions (one 6-step dependent chain)
__device__ __forceinline__ void waveRedSum3(float& a, float& b, float& c) {
#pragma unroll
    for (int o = 32; o > 0; o >>= 1) {
        a += __shfl_down(a, o, 64);
        b += __shfl_down(b, o, 64);
        c += __shfl_down(c, o, 64);
    }
    a = __shfl(a, 0, 64); b = __shfl(b, 0, 64); c = __shfl(c, 0, 64);
}
__device__ __forceinline__ void waveRedSum2(float& a, float& b) {
#pragma unroll
    for (int o = 32; o > 0; o >>= 1) {
        a += __shfl_down(a, o, 64);
        b += __shfl_down(b, o, 64);
    }
    a = __shfl(a, 0, 64); b = __shfl(b, 0, 64);
}
__device__ __forceinline__ float blockRedSum(float v, float* buf) {
    int lane = threadIdx.x & 63, wid = threadIdx.x >> 6;
#pragma unroll
    for (int o = 32; o > 0; o >>= 1) v += __shfl_down(v, o, 64);
    __syncthreads();
    if (lane == 0) buf[wid] = v;
    __syncthreads();
    int nw = blockDim.x >> 6;
    float s = buf[0];
    for (int i = 1; i < nw; i++) s += buf[i];
    return s;
}
__device__ __forceinline__ float blockRedMax(float v, float* buf) {
    int lane = threadIdx.x & 63, wid = threadIdx.x >> 6;
#pragma unroll
    for (int o = 32; o > 0; o >>= 1) v = fmaxf(v, __shfl_down(v, o, 64));
    __syncthreads();
    if (lane == 0) buf[wid] = v;
    __syncthreads();
    int nw = blockDim.x >> 6;
    float s = buf[0];
    for (int i = 1; i < nw; i++) s = fmaxf(s, buf[i]);
    return s;
}

// ---------------- bf16 MFMA GEMM (round-8 proven: BK=32, 16KB LDS) ----------------
// C[m,n] = sum_k A[m,k]*B'[k,n] (+bias[n]; biasB used when zb!=0). A,B row-major.
// NSPLIT>1 && !ATOMIC: partial sums to Cv + ks*cOff1 (separate buffers).
// XCD-aware block swizzle: physical flat id f -> logical (f&7)*(nblk/8)+(f>>3)
// so each XCD owns a contiguous tile range (all tiles of a z on one XCD's L2).
template <bool OUT_BF16, bool BIAS, bool ATOMIC, int NSPLIT, bool DUAL>
__global__ __launch_bounds__(256) void mfma_gemm(
    const short* __restrict__ A, int lda, int64_t sA,
    const short* __restrict__ B, int ldb, int64_t sB,
    void* __restrict__ Cv, int ldc, int64_t sC,
    const float* __restrict__ bias, int M, int N, int K,
    const short* __restrict__ A1, const short* __restrict__ B1, int64_t cOff1,
    const float* __restrict__ biasB)
{
    __shared__ short As[128][32];
    __shared__ short Bs[128][32];
    int bx = blockIdx.x, by = blockIdx.y, bz = blockIdx.z;
    {
        const int gx = gridDim.x, gy = gridDim.y;
        const int nblk = gx * gy * gridDim.z;
        if ((nblk & 7) == 0) {
            int flat = bx + gx * (by + gy * bz);
            int logical = (flat & 7) * (nblk >> 3) + (flat >> 3);
            bx = logical % gx; logical /= gx;
            by = logical % gy; bz = logical / gy;
        }
    }
    const int zz = bz;
    int zb, ks, half;
    if (DUAL) { half = zz & 1; zb = zz >> 1; ks = 0; }
    else      { zb = zz / NSPLIT; ks = zz - zb * NSPLIT; half = 0; }
    const short* Ap = (DUAL && half) ? A1 : A;
    const short* Bp = (DUAL && half) ? B1 : B;
    Ap += (int64_t)zb * sA;
    Bp += (int64_t)zb * sB;
    const int kper = K / NSPLIT;
    const int kbeg = ks * kper, kend = kbeg + kper;
    const int m0 = by * 128, n0 = bx * 128;
    const int t = threadIdx.x;
    const int lane = t & 63, w = t >> 6;
    const int wm = (w & 1) * 64, wn = (w >> 1) * 64;
    floatx4 acc[4][4] = {};
    for (int k0 = kbeg; k0 < kend; k0 += 32) {
        {
            int r = t >> 2, c8 = (t & 3) * 8;
            const short* ap = Ap + (int64_t)(m0 + r) * lda + k0 + c8;
            gload16(ap, &As[r][c8]);
            gload16(ap + (int64_t)64 * lda, &As[r + 64][c8]);
            const short* bp = Bp + (int64_t)(n0 + r) * ldb + k0 + c8;
            gload16(bp, &Bs[r][c8]);
            gload16(bp + (int64_t)64 * ldb, &Bs[r + 64][c8]);
        }
        __syncthreads();
        short8 af[4], bfv[4];
#pragma unroll
        for (int i = 0; i < 4; i++)
            af[i] = *(const short8*)&As[wm + 16 * i + (lane & 15)][8 * (lane >> 4)];
#pragma unroll
        for (int i = 0; i < 4; i++)
            bfv[i] = *(const short8*)&Bs[wn + 16 * i + (lane & 15)][8 * (lane >> 4)];
#pragma unroll
        for (int i = 0; i < 4; i++)
#pragma unroll
            for (int j = 0; j < 4; j++)
                acc[i][j] = __builtin_amdgcn_mfma_f32_16x16x32_bf16(af[i], bfv[j], acc[i][j], 0, 0, 0);
        __syncthreads();
    }
    const int q = lane >> 4, c = lane & 15;
    int64_t cbase = (int64_t)zb * sC + ((DUAL && half) ? cOff1 : 0);
    if (NSPLIT > 1 && !ATOMIC) cbase += (int64_t)ks * cOff1;
    const float* bsel = (BIAS && biasB && zb) ? biasB : bias;
#pragma unroll
    for (int j = 0; j < 4; j++) {
        int col = n0 + wn + 16 * j + c;
        float bv = BIAS ? bsel[col] : 0.0f;
#pragma unroll
        for (int i = 0; i < 4; i++) {
            int rowb = m0 + wm + 16 * i + 4 * q;
#pragma unroll
            for (int r = 0; r < 4; r++) {
                float v = acc[i][j][r] + bv;
                int64_t idx = cbase + (int64_t)(rowb + r) * ldc + col;
                if (ATOMIC)       atomicAdd((float*)Cv + idx, v);
                else if (OUT_BF16) ((ushort*)Cv)[idx] = f2bf(v);
                else               ((float*)Cv)[idx] = v;
            }
        }
    }
}

// ---------------- trig table (cos/sin of 2*pi*p/1024, bit-exact args) ----------------
__global__ __launch_bounds__(256) void trigtab_kernel(float* __restrict__ tab) {
    int p = blockIdx.x * 256 + threadIdx.x;   // grid 4 -> p in [0,1024)
    float ang = (6.28318530717958647692f / 1024.0f) * (float)p;
    tab[p] = cosf(ang);
    tab[1024 + p] = sinf(ang);
}

// ---------------- fused constants (table-driven) ----------------
// CS1 rows per block (no int div, k<544 only - GEMM reads K=544); C2/S2 via
// table idx 4p (2*pi/256*p == 2*pi/1024*4p bit-exact); W packs unchanged.
__global__ __launch_bounds__(256) void genconst_kernel(
    const float* __restrict__ tab,
    ushort* CS1c, ushort* CS1s, ushort* C2, ushort* S2,
    const float* __restrict__ WlW, const float* __restrict__ WsW, const float* __restrict__ WcW,
    ushort* Wl, ushort* Ws, ushort* Wc)
{
    __shared__ float lct[1024], lst[1024];
    int blk = blockIdx.x, t = threadIdx.x;
    if (blk < 704) {
        for (int i = t; i < 1024; i += 256) { lct[i] = tab[i]; lst[i] = tab[1024 + i]; }
        __syncthreads();
    }
    if (blk < 640) {
        int n = blk;
        for (int k = t; k < 544; k += 256) {
            float vc, vs;
            if (k <= 512) {
                int p = (n * k) & 1023;
                vc = lct[p];
                vs = (k == 0) ? 0.0f : -lst[p];
            } else { vc = 0.0f; vs = 0.0f; }
            CS1c[n * KF2 + k] = f2bf(vc);
            CS1s[n * KF2 + k] = f2bf(vs);
        }
    } else if (blk < 704) {
        int base = (blk - 640) * 1024;        // 64 blocks x 1024 = 256x256
#pragma unroll
        for (int i = 0; i < 4; i++) {
            int idx = base + t + 256 * i;
            int d = idx >> 8, j = idx & 255;
            int p = ((d * j) & 255) << 2;
            C2[idx] = f2bf(lct[p]);
            S2[idx] = f2bf(lst[p]);
        }
    } else {
        int r = blk - 704;                    // 512 rows
        const float* src; ushort* dst; int srow;
        if (r < 256)      { src = WlW; dst = Wl + r * KPAD;        srow = r + 1; }
        else if (r < 384) { src = WsW; dst = Ws + (r - 256) * KPAD; srow = r - 256 + 1; }
        else              { src = WcW; dst = Wc + (r - 384) * KPAD; srow = r - 384 + 1; }
        dst[t] = (t < DP) ? f2bf(src[(int64_t)srow * DP + t]) : (ushort)0;
        if (t < KPAD - 256) {
            int t2 = t + 256;
            dst[t2] = (t2 < DP) ? f2bf(src[(int64_t)srow * DP + t2]) : (ushort)0;
        }
    }
}

// input prep + m-fold, wave-per-(bp,z)
__global__ __launch_bounds__(256) void prep_fold_kernel(const float* __restrict__ sent,
                                                        const float* __restrict__ comm,
                                                        ushort* __restrict__ XC, ushort* __restrict__ XS) {
    int bp = blockIdx.x;                       // 0..512
    int z = blockIdx.y * 4 + (threadIdx.x >> 6);
    int lane = threadIdx.x & 63;
    int m2 = (1024 - bp) & 1023;
    const float* base = (z < 32) ? sent + (int64_t)z * 262144 : comm + (int64_t)(z - 32) * 262144;
    float4 a = *(const float4*)(base + bp * 256 + 4 * lane);
    float4 b = *(const float4*)(base + m2 * 256 + 4 * lane);
    if (z >= 32) {
        float s1 = a.x * a.x + a.y * a.y + a.z * a.z + a.w * a.w;
        float s2 = b.x * b.x + b.y * b.y + b.z * b.z + b.w * b.w;
        waveRedSum2(s1, s2);
        float yn1 = sqrtf(fmaxf(s1, 1e-15f));
        float f1 = artanh_clip(yn1) / yn1;
        a.x *= f1; a.y *= f1; a.z *= f1; a.w *= f1;
        float yn2 = sqrtf(fmaxf(s2, 1e-15f));
        float f2v = artanh_clip(yn2) / yn2;
        b.x *= f2v; b.y *= f2v; b.z *= f2v; b.w *= f2v;
    }
    int64_t o = ((int64_t)z * NFOLD + bp) * 256 + 4 * lane;
    bool single = (bp == 0) || (bp == 512);
    ushort4 oc;
    oc.x = f2bf(single ? a.x : a.x + b.x);
    oc.y = f2bf(single ? a.y : a.y + b.y);
    oc.z = f2bf(single ? a.z : a.z + b.z);
    oc.w = f2bf(single ? a.w : a.w + b.w);
    *(ushort4*)(XC + o) = oc;
    if (!single) {
        ushort4 os;
        os.x = f2bf(a.x - b.x); os.y = f2bf(a.y - b.y);
        os.z = f2bf(a.z - b.z); os.w = f2bf(a.w - b.w);
        *(ushort4*)(XS + o) = os;
    }
}

// euclid_to_lorentz, wave-per-row, n-fold combine, exp-based sinh/cosh
// (memory-bound at ~105 MB; wave-per-row form is the measured-best variant)
__global__ __launch_bounds__(256) void e2l_kernel(const ushort* __restrict__ YcYs,
                                                  ushort* __restrict__ Lsb, ushort* __restrict__ Lcb) {
    int64_t row = (int64_t)blockIdx.x * 4 + (threadIdx.x >> 6);   // 0..65535
    int lane = threadIdx.x & 63;
    int z = (int)(row >> 10), n = (int)(row & 1023);
    int np = (n <= 512) ? n : 1024 - n;
    float sgn = (n <= 512) ? 1.0f : -1.0f;
    const ushort* base = YcYs + (int64_t)z * 327680 + np * 256 + 4 * lane;
    ushort4 uc = *(const ushort4*)base;
    ushort4 us = *(const ushort4*)(base + 163840);
    float v0 = bf2f(uc.x) + sgn * bf2f(us.x);
    float v1 = bf2f(uc.y) + sgn * bf2f(us.y);
    float v2 = bf2f(uc.z) + sgn * bf2f(us.z);
    float v3 = bf2f(uc.w) + sgn * bf2f(us.w);
    float s = waveRedSum(v0 * v0 + v1 * v1 + v2 * v2 + v3 * v3);
    float xn = sqrtf(fmaxf(s, 1e-15f)) + 1e-5f;
    float sc = fminf(1.0f, 2.0f / xn);
    float s2 = fmaxf(s * sc * sc, 1e-15f);
    float vn = sqrtf(s2);
    float e = expf(vn);
    float ei = 1.0f / e;
    float shv = (vn < 1e-4f) ? 1.0f : (e - ei) * 0.5f / vn;
    float fac = shv * sc;
    ushort* ob = (row < 32768 ? Lsb + row * KPAD : Lcb + (row - 32768) * KPAD);
    ob[1 + 4 * lane + 0] = f2bf(fac * v0);
    ob[1 + 4 * lane + 1] = f2bf(fac * v1);
    ob[1 + 4 * lane + 2] = f2bf(fac * v2);
    ob[1 + 4 * lane + 3] = f2bf(fac * v3);
    if (lane == 0) ob[0] = f2bf((e + ei) * 0.5f);
    if (lane < KPAD - DP) ob[DP + lane] = 0;
}

// lorentz_linear time fill (in place on bf16 rows of 288)
__global__ __launch_bounds__(256) void lnorm_kernel(ushort* __restrict__ Llin_bf) {
    int64_t row = (int64_t)blockIdx.x * 4 + (threadIdx.x >> 6);
    int lane = threadIdx.x & 63;
    ushort* ob = Llin_bf + row * KPAD;
    float s = 0.f;
#pragma unroll
    for (int i = 0; i < 4; i++) { float v = bf2f(ob[1 + 4 * lane + i]); s += v * v; }
    s = waveRedSum(s);
    if (lane == 0) ob[0] = f2bf(sqrtf(s + 1.0f));
    if (lane < KPAD - DP) ob[DP + lane] = 0;
}

// fused to_poincare + transpose on H rows of 128 (HsA+HcA via z in [0,64)).
// Block = 32 rows x 128 cols of one z-batch. Sector-coalesced global access
// (4 consecutive lanes x 16B contiguous per instruction). Row norms via
// 3-step 8-lane shfl_xor. Writes normalized rows back in place AND transposed.
__global__ __launch_bounds__(256) void poincT_kernel(ushort* __restrict__ H, ushort* __restrict__ HT) {
    __shared__ ushort tile[32][132];   // pitch 132: 8B-aligned rows; phase-2 reads ~4-way (cheap)
    int z = blockIdx.y;                // 0..63
    int n0 = blockIdx.x * 32;
    ushort* ib = H + (int64_t)z * 131072;
    ushort* ob = HT + (int64_t)z * 131072;
    int t = threadIdx.x;
    {
        int row = t >> 3;              // 0..31
        int s0 = (t & 7) * 8;          // lanes 0-3 -> bytes 0..63 (full sector/instr)
        ushort* src = ib + (int64_t)(n0 + row) * 128;
        uint4 va = *(const uint4*)(src + s0);
        uint4 vb = *(const uint4*)(src + s0 + 64);
        float fa[8], fb[8];
        const ushort* pa = (const ushort*)&va;
        const ushort* pb = (const ushort*)&vb;
        float s = 0.f;
#pragma unroll
        for (int i = 0; i < 8; i++) {
            fa[i] = bf2f(pa[i]); fb[i] = bf2f(pb[i]);
            s += fa[i] * fa[i] + fb[i] * fb[i];
        }
        s += __shfl_xor(s, 1, 64);
        s += __shfl_xor(s, 2, 64);
        s += __shfl_xor(s, 4, 64);
        float inv = 1.0f / (sqrtf(s + 1.0f) + 1.0f);
        ushort ga[8], gb[8];
#pragma unroll
        for (int i = 0; i < 8; i++) { ga[i] = f2bf(fa[i] * inv); gb[i] = f2bf(fb[i] * inv); }
        *(uint4*)(src + s0) = *(const uint4*)ga;
        *(uint4*)(src + s0 + 64) = *(const uint4*)gb;
        *(ushort4*)&tile[row][s0] = *(const ushort4*)&ga[0];
        *(ushort4*)&tile[row][s0 + 4] = *(const ushort4*)&ga[4];
        *(ushort4*)&tile[row][s0 + 64] = *(const ushort4*)&gb[0];
        *(ushort4*)&tile[row][s0 + 68] = *(const ushort4*)&gb[4];
    }
    __syncthreads();
    {
#pragma unroll
        for (int p = 0; p < 2; p++) {
            int j = p * 64 + (t >> 2);     // out row 0..127
            int nq = (t & 3) * 8;          // 4 lanes cover 32 ushorts = one 64B sector
            ushort g[8];
#pragma unroll
            for (int k = 0; k < 8; k++) g[k] = tile[nq + k][j];
            *(uint4*)(ob + (int64_t)j * 1024 + n0 + nq) = *(const uint4*)g;
        }
    }
}

// per-batch 1024x1024 bf16 gelu + transpose, 64x64 tiles.
// Sector-coalesced: every global load/store instruction covers full 64B sectors
// (4 consecutive lanes x 16B contiguous per row). Partials folded over the 4
// consecutive lanes via shfl_xor. 16 chunks per batch.
__global__ __launch_bounds__(256) void tmat_kernel(ushort* __restrict__ inout, ushort* __restrict__ outp,
                                                   float* __restrict__ rowpart, float* __restrict__ colpart) {
    __shared__ ushort tile[64][68];   // pitch 68 ushorts: 8B-aligned vector writes
    int z = blockIdx.z;
    int r0 = blockIdx.x * 64, c0 = blockIdx.y * 64;
    ushort* ib = inout + (int64_t)z * 1048576;
    ushort* ob = outp + (int64_t)z * 1048576;
    int t = threadIdx.x;
    int row = t >> 2;            // 0..63
    int cq = (t & 3) * 8;        // 8-ushort (16B) segment; lanes 0-3 -> 64B contiguous
    {
        ushort* src = ib + (int64_t)(r0 + row) * 1024 + c0;
        float rsum = 0.f;
#pragma unroll
        for (int s = 0; s < 2; s++) {
            int cb = cq + 32 * s;
            uint4 v = *(const uint4*)(src + cb);
            ushort g[8];
            const ushort* pv = (const ushort*)&v;
#pragma unroll
            for (int k = 0; k < 8; k++) {
                g[k] = f2bf(gelu_f(bf2f(pv[k])));
                float fb = bf2f(g[k]);
                if (!(c0 == 0 && cb == 0 && k == 0)) rsum += fb * fb;  // exclude global col 0
            }
            *(uint4*)(src + cb) = *(const uint4*)g;            // gelu'd row-major write-back
            *(ushort4*)&tile[row][cb] = *(const ushort4*)&g[0];
            *(ushort4*)&tile[row][cb + 4] = *(const ushort4*)&g[4];
        }
        rsum += __shfl_xor(rsum, 1, 64);
        rsum += __shfl_xor(rsum, 2, 64);
        if ((t & 3) == 0)
            rowpart[((int64_t)(z * 16 + blockIdx.y)) * 1024 + r0 + row] = rsum;
    }
    __syncthreads();
    {
        int i2 = row;            // out-row within tile (orig col c0+i2)
        ushort* dst = ob + (int64_t)(c0 + i2) * 1024 + r0;
        float csum = 0.f;
#pragma unroll
        for (int s = 0; s < 2; s++) {
            int cb = cq + 32 * s;
            ushort g[8];
#pragma unroll
            for (int k = 0; k < 8; k++) {
                g[k] = tile[cb + k][i2];
                float a = bf2f(g[k]);
                csum += a * a;
            }
            *(uint4*)(dst + cb) = *(const uint4*)g;            // full 64B sector per 4 lanes
        }
        csum += __shfl_xor(csum, 1, 64);
        csum += __shfl_xor(csum, 2, 64);
        if ((t & 3) == 0)
            colpart[((int64_t)(z * 16 + blockIdx.x)) * 1024 + c0 + i2] = csum;
    }
}

// fold partials: write time col into Lmat + LmatT row0, xnrow, final colsum
// (col 0 of colsum = sum of time^2, computed here exactly). 16 chunks per batch.
__global__ __launch_bounds__(256) void combine_kernel(
    const float* __restrict__ rowpart, const float* __restrict__ colpart,
    ushort* __restrict__ Lmat, ushort* __restrict__ LmatT,
    float* __restrict__ xnrow, float* __restrict__ colsum)
{
    __shared__ float red[4];
    int b = blockIdx.x, t = threadIdx.x;
    float t2 = 0.f;
#pragma unroll
    for (int i = 0; i < 4; i++) {
        int n = t + 256 * i;
        const float* rp = rowpart + (int64_t)b * 16384 + n;
        float s = 0.f;
#pragma unroll
        for (int c = 0; c < 16; c++) s += rp[c * 1024];
        float tim = sqrtf(1.0f + s);
        ushort tb = f2bf(tim);
        Lmat[((int64_t)(b * 1024 + n)) * 1024] = tb;
        LmatT[(int64_t)b * 1048576 + n] = tb;
        xnrow[b * 1024 + n] = sqrtf(fmaxf(1.0f + 2.0f * s, 1e-15f));
        t2 += tim * tim;
    }
#pragma unroll
    for (int i = 0; i < 4; i++) {
        int m = t + 256 * i;
        const float* cp = colpart + (int64_t)b * 16384 + m;
        float s = 0.f;
#pragma unroll
        for (int c = 0; c < 16; c++) s += cp[c * 1024];
        if (m > 0) colsum[b * 1024 + m] = s;
    }
    float tt = blockRedSum(t2, red);
    if (t == 0) colsum[b * 1024] = tt;
}

// column factor for mobius scale: fac_c[b,m] (reads precomputed colsum)
__global__ __launch_bounds__(256) void colfac_kernel(const float* __restrict__ colsum,
                                                     const float* __restrict__ mxcT,
                                                     float* __restrict__ fac_c) {
    int b = blockIdx.x; int m = blockIdx.y * 256 + threadIdx.x;
    float xn = sqrtf(fmaxf(colsum[b * NCQ + m], 1e-15f));
    const float* base = mxcT + (int64_t)b * KQ * NCQ + m;
    const float* base2 = base + MXSPLIT;
    float sm = 0.f;
    for (int j = 0; j < KQ; j++) {
        float v = base[j * NCQ] + base2[j * NCQ];
        sm += v * v;
    }
    float mxn = sqrtf(fmaxf(sm, 1e-15f));
    fac_c[b * NCQ + m] = tanhf(mxn / xn * artanh_clip(xn)) / mxn;
}

// Hs path rowwise chain -> logits.
// 8 rows per wave (8 lanes/row, 16 elems/lane): per-row transcendental chain
// amortized 8x; reductions are 3-step 8-lane shfl_xor trees.
__global__ __launch_bounds__(256) void rowops_s_kernel(
    const ushort* __restrict__ Hsa, const float* __restrict__ mxs,
    const float* __restrict__ xnrow, const float* __restrict__ whs,
    float* __restrict__ logits)
{
    const int t = threadIdx.x;
    const int lane = t & 63;
    const int wid = t >> 6;
    const int sub = lane & 7;         // lane within row-group
    const int rg  = lane >> 3;        // row within wave (0..7)
    const int64_t row = (int64_t)blockIdx.x * 32 + wid * 8 + rg;
    const ushort* p = Hsa + row * KQ + sub * 16;
    const float*  q = mxs + row * KQ + sub * 16;

    float pf[16], qf[16];
    {
        uint4 u0 = *(const uint4*)p;
        uint4 u1 = *(const uint4*)(p + 8);
        const ushort* pu0 = (const ushort*)&u0;
        const ushort* pu1 = (const ushort*)&u1;
#pragma unroll
        for (int i = 0; i < 8; i++) { pf[i] = bf2f(pu0[i]); pf[8 + i] = bf2f(pu1[i]); }
    }
#pragma unroll
    for (int i = 0; i < 16; i += 4) {
        float4 a  = *(const float4*)(q + i);
        float4 b2 = *(const float4*)(q + i + MXSPLIT);
        qf[i + 0] = a.x + b2.x; qf[i + 1] = a.y + b2.y;
        qf[i + 2] = a.z + b2.z; qf[i + 3] = a.w + b2.w;
    }
    // Round A: R1=sum q^2, R2=sum p*q, R3=sum p^2
    float r1 = 0.f, r2 = 0.f, r3 = 0.f;
#pragma unroll
    for (int i = 0; i < 16; i++) {
        r1 += qf[i] * qf[i]; r2 += pf[i] * qf[i]; r3 += pf[i] * pf[i];
    }
#pragma unroll
    for (int o = 4; o > 0; o >>= 1) {
        r1 += __shfl_xor(r1, o, 64);
        r2 += __shfl_xor(r2, o, 64);
        r3 += __shfl_xor(r3, o, 64);
    }
    float mxn = sqrtf(fmaxf(r1, 1e-15f));
    float xn = xnrow[row];
    float fac = tanhf(mxn / xn * artanh_clip(xn)) / mxn;
    float xy = fac * r2;
    float x2 = r3;
    float y2 = fac * fac * r1;
    float ca = 1.f + 2.f * xy + y2, cb = 1.f - x2;
    float den = fmaxf(1.f + 2.f * xy + x2 * y2, 1e-15f);
    float hn2 = (ca * ca * x2 + 2.f * ca * cb * xy + cb * cb * y2) / (den * den);
    float hn = sqrtf(fmaxf(hn2, 1e-15f));
    float uf = artanh_clip(hn) / hn;
    float ufd = uf / den;
    float cbf = cb * fac;
    float wv[16];
#pragma unroll
    for (int i = 0; i < 16; i += 4) *(float4*)&wv[i] = *(const float4*)(whs + sub * 16 + i);
    // Round B: R4=sum g^2, R5=sum g*whs
    float r4 = 0.f, r5 = 0.f;
#pragma unroll
    for (int i = 0; i < 16; i++) {
        float g = gelu_f(ufd * (ca * pf[i] + cbf * qf[i]));
        r4 += g * g;
        r5 += g * wv[i];
    }
#pragma unroll
    for (int o = 4; o > 0; o >>= 1) {
        r4 += __shfl_xor(r4, o, 64);
        r5 += __shfl_xor(r5, o, 64);
    }
    float gn = sqrtf(fmaxf(r4, 1e-15f));
    float ef = tanhf(gn) / gn;
    float dot = ef * r5;
    float Hn = sqrtf(fmaxf(ef * ef * r4, 1e-15f));
    float mxn2 = sqrtf(fmaxf(dot * dot, 1e-15f));
    float lg = tanhf(mxn2 / Hn * artanh_clip(Hn)) * dot / mxn2;
    if (sub == 0) logits[row] = lg;
}

// Hc path rowwise chain: wave-per-row (16 elems/lane), applies fac on the fly,
// reads two mx splits, writes combined Hc into split A. 2 reduction rounds.
__global__ __launch_bounds__(256) void rowops_c_kernel(const ushort* __restrict__ HcAT,
                                                       float* __restrict__ mx,
                                                       const float* __restrict__ fac_c) {
    int64_t row = (int64_t)blockIdx.x * 4 + (threadIdx.x >> 6);   // 0..4095
    int lane = threadIdx.x & 63;
    int b = (int)(row >> 7);
    const ushort* xb = HcAT + row * (int64_t)NCQ + 16 * lane;
    float* yb = mx + row * (int64_t)NCQ + 16 * lane;
    const float* fb = fac_c + b * NCQ + 16 * lane;
    float xv[16], yv[16];
    {
        uint4 u0 = *(const uint4*)xb;
        uint4 u1 = *(const uint4*)(xb + 8);
        const ushort* pu0 = (const ushort*)&u0;
        const ushort* pu1 = (const ushort*)&u1;
#pragma unroll
        for (int i = 0; i < 8; i++) { xv[i] = bf2f(pu0[i]); xv[8 + i] = bf2f(pu1[i]); }
    }
#pragma unroll
    for (int i = 0; i < 16; i += 4) {
        float4 v1 = *(const float4*)(yb + i);
        float4 v2 = *(const float4*)(yb + i + MXSPLIT);
        float4 fv = *(const float4*)(fb + i);
        yv[i + 0] = fv.x * (v1.x + v2.x);
        yv[i + 1] = fv.y * (v1.y + v2.y);
        yv[i + 2] = fv.z * (v1.z + v2.z);
        yv[i + 3] = fv.w * (v1.w + v2.w);
    }
    // Round A: xy, x2, y2 (interleaved)
    float xy = 0.f, x2 = 0.f, y2 = 0.f;
#pragma unroll
    for (int i = 0; i < 16; i++) { xy += xv[i] * yv[i]; x2 += xv[i] * xv[i]; y2 += yv[i] * yv[i]; }
    waveRedSum3(xy, x2, y2);
    float ca = 1.f + 2.f * xy + y2, cb = 1.f - x2;
    float den = fmaxf(1.f + 2.f * xy + x2 * y2, 1e-15f);
    float hn2 = (ca * ca * x2 + 2.f * ca * cb * xy + cb * cb * y2) / (den * den);
    float hn = sqrtf(fmaxf(hn2, 1e-15f));
    float uf = artanh_clip(hn) / hn;
    float g[16]; float gn2 = 0.f;
#pragma unroll
    for (int i = 0; i < 16; i++) {
        float h = (ca * xv[i] + cb * yv[i]) / den;
        g[i] = gelu_f(uf * h);
        gn2 += g[i] * g[i];
    }
    gn2 = waveRedSum(gn2);
    float gn = sqrtf(fmaxf(gn2, 1e-15f));
    float ef = tanhf(gn) / gn;
#pragma unroll
    for (int i = 0; i < 16; i += 4) {
        float4 o = {ef * g[i], ef * g[i + 1], ef * g[i + 2], ef * g[i + 3]};
        *(float4*)(yb + i) = o;
    }
}

// Ac logits
__global__ __launch_bounds__(256) void logitsc_kernel(const float* __restrict__ Hc, const float* __restrict__ whc, float* __restrict__ lgc) {
    int b = blockIdx.x; int m = blockIdx.y * 256 + threadIdx.x;
    const float* base = Hc + (int64_t)b * KQ * NCQ + m;
    float s1 = 0.f, s2 = 0.f;
    for (int j = 0; j < KQ; j++) { float v = base[j * NCQ]; s1 += v * whc[j]; s2 += v * v; }
    float xn = sqrtf(fmaxf(s2, 1e-15f));
    float mxn = sqrtf(fmaxf(s1 * s1, 1e-15f));
    lgc[b * NCQ + m] = tanhf(mxn / xn * artanh_clip(xn)) * s1 / mxn;
}

// fused softmax for lgs|lgc -> AsOut|AcOut, grid 64
__global__ __launch_bounds__(256) void softmax_kernel(const float* __restrict__ lg, float* __restrict__ outp) {
    __shared__ float red[4];
    int b = blockIdx.x; int t = threadIdx.x;
    const float* x = lg + b * 1024;
    float v[4]; float m = -1e30f;
#pragma unroll
    for (int i = 0; i < 4; i++) { v[i] = x[t + 256 * i]; m = fmaxf(m, v[i]); }
    m = blockRedMax(m, red);
    float s = 0.f;
#pragma unroll
    for (int i = 0; i < 4; i++) { v[i] = expf(v[i] - m); s += v[i]; }
    s = blockRedSum(s, red);
    float inv = 1.0f / s;
#pragma unroll
    for (int i = 0; i < 4; i++) outp[b * 1024 + t + 256 * i] = v[i] * inv;
}

// centroid stage A on bf16 L (stride 288, time at col 0)
__global__ __launch_bounds__(320) void centroidA_kernel(
    const ushort* __restrict__ Lsb, const ushort* __restrict__ Lcb,
    const float* __restrict__ As, const float* __restrict__ Ac,
    float* __restrict__ part)
{
    int b = blockIdx.x;
    int which = blockIdx.y;
    int chunk = blockIdx.z;
    const ushort* L = which ? Lcb : Lsb;
    const float* w = which ? Ac : As;
    int t = threadIdx.x;
    if (t >= DP) return;
    const ushort* Lb = L + (int64_t)b * NSQ * KPAD + (int64_t)chunk * 128 * KPAD + t;
    const float* wb = w + b * NSQ + chunk * 128;
    float s = 0.f;
    for (int n = 0; n < 128; n++) s += wb[n] * bf2f(Lb[(int64_t)n * KPAD]);
    part[((int64_t)((b * 2 + which) * 8 + chunk)) * 264 + t] = s;
}
__global__ __launch_bounds__(320) void centroidB_kernel(
    const float* __restrict__ part, float* __restrict__ co_s, float* __restrict__ co_c)
{
    int b = blockIdx.x;
    int which = blockIdx.y;
    int t = threadIdx.x;
    if (t >= DP) return;
    const float* p = part + (int64_t)(b * 2 + which) * 8 * 264 + t;
    float s = 0.f;
#pragma unroll
    for (int c = 0; c < 8; c++) s += p[c * 264];
    (which ? co_c : co_s)[b * DP + t] = s;
}

__global__ __launch_bounds__(256) void final_kernel(const float* __restrict__ co_s, const float* __restrict__ co_c, float* __restrict__ outp) {
    __shared__ float red[4];
    int b = blockIdx.x, t = threadIdx.x;
    float zmine[2];
    for (int w = 0; w < 2; w++) {
        const float* co = (w ? co_c : co_s) + b * DP;
        float at = co[0];
        float asp = co[1 + t];
        float ssp = blockRedSum(asp * asp, red);
        float li = ssp - at * at;
        float den = sqrtf(fmaxf(fabsf(li), 1e-8f));
        float xt = at / den, xsp = asp / den;
        float s2 = blockRedSum(xsp * xsp, red);
        float nrm = sqrtf(fmaxf(s2, 1e-15f));
        float ac = acoshf(fmaxf(xt, 1.0f + 1e-7f));
        zmine[w] = ac * xsp / nrm;
    }
    float vn2 = blockRedSum(zmine[0] * zmine[0] + zmine[1] * zmine[1], red);
    float vn = sqrtf(fmaxf(vn2, 1e-15f));
    float sc = sinhf(vn) / vn;
    if (t == 0) outp[b * 513] = coshf(vn);
    outp[b * 513 + 1 + t] = sc * zmine[0];
    outp[b * 513 + 1 + 256 + t] = sc * zmine[1];
}

// ---------------- host launcher ----------------
extern "C" void kernel_launch(void* const* d_in, const int* in_sizes, int n_in,
                              void* d_out, int out_size, void* d_ws, size_t ws_size,
                              hipStream_t stream)
{
    const float* sent = (const float*)d_in[0];
    const float* comm = (const float*)d_in[1];
    const float* WlW  = (const float*)d_in[2];
    const float* Wlb  = (const float*)d_in[3];
    const float* WcW  = (const float*)d_in[4];
    const float* Wcb  = (const float*)d_in[5];
    const float* WsW  = (const float*)d_in[6];
    const float* Wsb  = (const float*)d_in[7];
    const float* whs  = (const float*)d_in[8];
    const float* whc  = (const float*)d_in[9];
    float* out = (float*)d_out;
    (void)in_sizes; (void)n_in; (void)out_size; (void)ws_size;

    float* ws = (float*)d_ws;
    size_t off = 0;
    auto take = [&](size_t n) { float* p = ws + off; off += n; return p; };
    float*  xnrow = take(32768);
    float*  fac_c = take(32768);
    float*  lgs   = take(32768);   // contiguous with lgc
    float*  lgc   = take(32768);
    float*  co_s  = take(8224);
    float*  co_c  = take(8224);
    float*  trigtab = take(2048);
    ushort* Ls_bf = (ushort*)take(4718592);   // contiguous with Lc_bf
    ushort* Lc_bf = (ushort*)take(4718592);
    ushort* Wl_bf = (ushort*)take(36864);
    ushort* Ws_bf = (ushort*)take(18432);
    ushort* Wc_bf = (ushort*)take(18432);
    ushort* HsA_bf = (ushort*)take(2097152);  // contiguous with HcA_bf
    ushort* HcA_bf = (ushort*)take(2097152);
    float*  part_cn   = take(1048576);        // rowpart (32 x 16 x 1024 used)
    float*  part_cent = take(135168);
    ushort* LmatT_bf  = (ushort*)take(16777216);  // 32x1024x1024 bf16
    float*  F     = take(33554432);               // total ~249 MiB

    // Phase overlays in F (float offsets)
    ushort* XC_bf   = (ushort*)F;                 // [P1] 5.24M fl
    ushort* XS_bf   = (ushort*)(F + 5242880);     // [P1] 5.24M fl
    ushort* Ff_bf   = (ushort*)(F + 10485760);    // [P1] 10.49M fl
    ushort* CS1c    = (ushort*)(F + 20971520);    // [P1] 204800 fl
    ushort* CS1s    = (ushort*)(F + 21176320);    // [P1] 204800 fl
    ushort* C2_bf   = (ushort*)(F + 21381120);    // [P1] 32k fl
    ushort* S2_bf   = (ushort*)(F + 21413888);    // [P1] 32k fl
    ushort* YcYs    = (ushort*)F;                 // [P1] aliases XC/XS; 10.49M fl
    ushort* Lmat_bf = (ushort*)F;                 // [P3-P5] 16.78M fl
    ushort* Llin_bf = (ushort*)(F + 29360128);    // [P2-P3] 4.72M fl (dead after Lmat GEMM)
    float*  mx      = F + 16777216;               // [P5] 2 x 4.19M fl split buffers
    ushort* HsAT    = (ushort*)(F + 25165824);    // [P5] 2.1M fl (contiguous with HcAT)
    ushort* HcAT    = (ushort*)(F + 27262976);    // [P5] 2.1M fl
    float*  colpart = F + 29360128;               // [P4-P5] 524288 fl (reuses dead Llin)
    float*  colsum  = F + 30408704;               // [P4-P5] 32k fl

    float* AsOut = out + 16416;
    float* AcOut = out + 16416 + 32768;

    dim3 blk(256);
    const short* NUL = nullptr;

    trigtab_kernel<<<4, 256, 0, stream>>>(trigtab);
    genconst_kernel<<<1216, 256, 0, stream>>>(trigtab, CS1c, CS1s, C2_bf, S2_bf,
                                              WlW, WsW, WcW, Wl_bf, Ws_bf, Wc_bf);

    // ---- input prep + m-fold ----
    prep_fold_kernel<<<dim3(513, 16), blk, 0, stream>>>(sent, comm, XC_bf, XS_bf);
    // stage-1 DUAL: Ff[:, :640] = C2 . XC^T ; Ff[:, 640:] = S2 . XS^T
    mfma_gemm<true,false,false,1,true><<<dim3(5,2,128), blk, 0, stream>>>(
        (const short*)C2_bf,256,0, (const short*)XC_bf,256,(int64_t)NFOLD*256, Ff_bf,1280,(int64_t)256*1280,
        nullptr, 256,NFOLD,256, (const short*)S2_bf, (const short*)XS_bf, 640, nullptr);
    // stage-2 DUAL (n-folded): Yc = CS1c . Fc^T ; Ys = CS1s . Fs^T
    // K trimmed 640->544: CS1c/CS1s cols >=513 are exactly zero -> bit-exact result.
    mfma_gemm<true,false,false,1,true><<<dim3(2,5,128), blk, 0, stream>>>(
        (const short*)CS1c,KF2,0, (const short*)Ff_bf,1280,(int64_t)256*1280, YcYs,256,327680,
        nullptr, NFOLD,256,544, (const short*)CS1s, (const short*)(Ff_bf+640), 163840, nullptr);
    e2l_kernel<<<16384, blk, 0, stream>>>(YcYs, Ls_bf, Lc_bf);

    // ---- L = lorentz_linear(Lc, Wl): space cols bf16 straight into Llin_bf[.,1:] ----
    mfma_gemm<true,true,false,1,false><<<dim3(2,256,1), blk, 0, stream>>>(
        (const short*)Lc_bf,KPAD,0, (const short*)Wl_bf,KPAD,0, (void*)(Llin_bf+1),KPAD,0,
        Wlb+1, 32768,256,KPAD, NUL, NUL, 0, nullptr);
    lnorm_kernel<<<8192, blk, 0, stream>>>(Llin_bf);

    // ---- Lmat = einsum(Ls, Llin) RAW in bf16 (plain scalar epilogue; gelu in tmat) ----
    mfma_gemm<true,false,false,1,false><<<dim3(8,8,32), blk, 0, stream>>>(
        (const short*)Ls_bf,KPAD,294912, (const short*)Llin_bf,KPAD,294912, Lmat_bf,1024,1048576,
        nullptr, 1024,1024,KPAD, NUL, NUL, 0, nullptr);
    // gelu + transpose + write-back + fused row/col sumsq partials, then fold
    tmat_kernel<<<dim3(16,16,32), blk, 0, stream>>>(Lmat_bf, LmatT_bf, part_cn, colpart);
    combine_kernel<<<32, blk, 0, stream>>>(part_cn, colpart, Lmat_bf, LmatT_bf, xnrow, colsum);

    // ---- Hs_a / Hc_a: bf16 + per-z bias straight into HsA_bf|HcA_bf ----
    mfma_gemm<true,true,false,1,false><<<dim3(1,256,2), blk, 0, stream>>>(
        (const short*)Ls_bf,KPAD,9437184, (const short*)Ws_bf,KPAD,36864, HsA_bf,128,4194304,
        Wsb+1, 32768,128,KPAD, NUL, NUL, 0, Wcb+1);
    // fused poincare-normalize + transpose (HsA->HsAT, HcA->HcAT in one launch)
    poincT_kernel<<<dim3(32,64), blk, 0, stream>>>(HsA_bf, HsAT);

    // ---- Hs path: mx_s = Lmat . Hc_a (split-K=2, dual partial buffers) ----
    mfma_gemm<false,false,false,2,false><<<dim3(1,8,64), blk, 0, stream>>>(
        (const short*)Lmat_bf,1024,1048576, (const short*)HcAT,1024,131072, mx,128,131072,
        nullptr, 1024,128,1024, NUL, NUL, MXSPLIT, nullptr);
    rowops_s_kernel<<<1024, blk, 0, stream>>>(HsA_bf, mx, xnrow, whs, lgs);

    // ---- Hc path: mx_cT = Hs_a^T . Lmat (all-fast via HsAT + LmatT; split-K=2) ----
    mfma_gemm<false,false,false,2,false><<<dim3(8,1,64), blk, 0, stream>>>(
        (const short*)HsAT,1024,131072, (const short*)LmatT_bf,1024,1048576, mx,1024,131072,
        nullptr, 128,1024,1024, NUL, NUL, MXSPLIT, nullptr);
    colfac_kernel<<<dim3(32,4), blk, 0, stream>>>(colsum, mx, fac_c);
    rowops_c_kernel<<<1024, blk, 0, stream>>>(HcAT, mx, fac_c);
    logitsc_kernel<<<dim3(32,4), blk, 0, stream>>>(mx, whc, lgc);

    // ---- softmaxes / centroids / concat ----
    softmax_kernel<<<64, blk, 0, stream>>>(lgs, AsOut);
    centroidA_kernel<<<dim3(32,2,8), 320, 0, stream>>>(Ls_bf, Lc_bf, AsOut, AcOut, part_cent);
    centroidB_kernel<<<dim3(32,2), 320, 0, stream>>>(part_cent, co_s, co_c);
    final_kernel<<<32, blk, 0, stream>>>(co_s, co_c, out);
}